// Round 11
// baseline (431.700 us; speedup 1.0000x reference)
//
#include <hip/hip_runtime.h>
#include <hip/hip_bf16.h>
#include <math.h>

#define BB 4
#define QQ 75
#define NBQ 300        // BB*QQ
#define CC 640
#define HW 121
#define NW 5
#define KS 5
#define SS 25          // NW*KS
#define MS 605         // KS*HW
#define JT 3025        // NW*MS
#define NPAIR 38       // query pairs per episode (75 -> 37 full + 1 dup)
#define PAIRS_PER_XCD 19  // 152 pairs / 8 XCDs

typedef __attribute__((ext_vector_type(8))) short short8;
typedef __attribute__((ext_vector_type(4))) float f32x4;

// workspace float offsets
#define OFF_SBF   0
#define SBF_F     (BB*JT*CC/2)            // bf16 storage
#define OFF_QBF   (OFF_SBF + SBF_F)
#define QBF_F     (NBQ*HW*CC/2)
#define OFF_P     (OFF_QBF + QBF_F)       // float4 partials [300][5][121]
// norm partials [400][4][128] f32 alias the pout region (dead until simi)
#define OFF_NRM   OFF_P

__device__ __forceinline__ void async16(const void* g, void* l) {
    __builtin_amdgcn_global_load_lds(
        (const __attribute__((address_space(1))) unsigned int*)g,
        (__attribute__((address_space(3))) unsigned int*)l, 16, 0, 0);
}

// ---------------------------------------------------------------------------
// Prep split (R5): wide-grid norm partials + scale/transpose/bf16 pack.
// Bit-exact with the original: (A0+A2)+(A1+A3) == old T[0]+T[1].
__global__ void norm_kernel(const float* __restrict__ sup, const float* __restrict__ qry,
                            float* __restrict__ nrm, float* __restrict__ out)
{
    const int blk = blockIdx.x;          // 0..1599 = col*4 + r
    const int col = blk >> 2, r = blk & 3;
    const int hw  = threadIdx.x;         // 128
    if (blk == 0 && hw == 0) out[0] = 0.f;   // replaces memset dispatch
    const float* src = (col < BB * SS)
        ? sup + (size_t)col * (CC * HW)
        : qry + (size_t)(col - BB * SS) * (CC * HW);
    float ss = 0.f;
    if (hw < HW) {
        const float* p = src + hw;
#pragma unroll 16
        for (int i = 0; i < CC / 4; ++i) {
            const float v = p[(size_t)(r + i * 4) * HW];
            ss = fmaf(v, v, ss);
        }
    }
    nrm[((size_t)col * 4 + r) * 128 + hw] = ss;
}

__global__ void scale_kernel(const float* __restrict__ sup, const float* __restrict__ qry,
                             const float* __restrict__ nrm,
                             __hip_bfloat16* __restrict__ Sbf, __hip_bfloat16* __restrict__ Qbf)
{
    const int blk = blockIdx.x;      // 0..1599 = col*4 + qtr
    const int col = blk >> 2, qtr = blk & 3;
    const int t   = threadIdx.x;     // 256
    const float* src;
    __hip_bfloat16* dst;
    if (col < BB * SS) {
        const int b = col / SS, s = col % SS;
        const int n = s / KS, k = s % KS;
        src = sup + (size_t)col * (CC * HW);
        dst = Sbf + ((size_t)b * JT + n * MS + k * HW) * CC;
    } else {
        const int bq = col - BB * SS;
        src = qry + (size_t)bq * (CC * HW);
        dst = Qbf + (size_t)bq * (HW * CC);
    }

    __shared__ float inv[128];
    __shared__ float T[32][128];

    if (t < 128) {
        const float p0 = nrm[((size_t)col * 4 + 0) * 128 + t];
        const float p1 = nrm[((size_t)col * 4 + 1) * 128 + t];
        const float p2 = nrm[((size_t)col * 4 + 2) * 128 + t];
        const float p3 = nrm[((size_t)col * 4 + 3) * 128 + t];
        inv[t] = (t < HW) ? 1.f / (sqrtf((p0 + p2) + (p1 + p3)) + 1e-8f) : 0.f;
    }

    for (int it = 0; it < 5; ++it) {
        const int c0 = qtr * 160 + it * 32;
        __syncthreads();                 // first pass also fences inv[]
#pragma unroll
        for (int i = 0; i < 16; ++i) {
            int idx = t + i * 256;
            int cc = idx >> 7, hw = idx & 127;
            if (hw < HW) T[cc][hw] = src[(size_t)(c0 + cc) * HW + hw] * inv[hw];
        }
        __syncthreads();
        const int hw = t >> 1, half = t & 1;
        if (hw < HW) {
            __hip_bfloat16 hv[16];
#pragma unroll
            for (int i = 0; i < 16; ++i) hv[i] = __float2bfloat16(T[half * 16 + i][hw]);
            int4* op = reinterpret_cast<int4*>(dst + (size_t)hw * CC + c0 + half * 16);
            op[0] = reinterpret_cast<int4*>(hv)[0];
            op[1] = reinterpret_cast<int4*>(hv)[1];
        }
    }
}

// ---------------------------------------------------------------------------
// R10: SMALL-BLOCK paired tile for a ONE-ROUND dispatch. 760 blocks on only
// 512 resident slots (8-wave blocks, reg-capped 2/CU) forced a 2-round wall
// at 74% utilization. Shrink to 4-wave (256-thr) blocks, wave tile 64m x 64j,
// j-window 64/pass: LDS 40 KB (dbuf 2x(16A+4B)) -> 3-4 blocks/CU -> 768-1024
// slots >= 760 blocks -> all blocks resident, wall = ONE block duration.
// Same verified 4x4 acc / fragment / swizzle structure (VGPR budget
// unchanged -> no R2-style spill). Each wave owns its full j-window, so the
// cross-wave LDS merge vanishes. 3-4 independent blocks/CU also provide
// barrier-free inter-block pipe overlap. Dbuf => trailing barrier back
// (2/chunk; barrier count was proven perf-neutral in R9).
__launch_bounds__(256, 4)
__global__ void simi_kernel(const __hip_bfloat16* __restrict__ Sbf,
                            const __hip_bfloat16* __restrict__ Qbf,
                            float4* __restrict__ pout)
{
    const int xcd   = blockIdx.x & 7;
    const int local = blockIdx.x >> 3;          // 0..94
    const int n     = local % NW;
    const int pair  = xcd * PAIRS_PER_XCD + local / NW;   // 0..151
    const int b     = pair / NPAIR;
    const int pi    = pair % NPAIR;
    const bool dup  = (pi == NPAIR - 1);        // 38th pair: q1 duplicates q0
    const int q0    = 2 * pi;
    const int q1    = dup ? q0 : q0 + 1;
    const int bq0   = b * QQ + q0;
    const int bq1   = b * QQ + q1;

    const int tid  = threadIdx.x;
    const int lane = tid & 63, wid = tid >> 6;  // 4 waves
    const int l15 = lane & 15, l4 = lane >> 4;
    const int wm0 = wid * 64;                   // wave query-col base (0..192)

    const unsigned short* qb0 = (const unsigned short*)(Qbf + (size_t)bq0 * (HW * CC));
    const unsigned short* qb1 = (const unsigned short*)(Qbf + (size_t)bq1 * (HW * CC));
    const unsigned short* sbase = (const unsigned short*)(Sbf + ((size_t)b * JT + n * MS) * CC);

    __shared__ __align__(16) unsigned short AsBuf[2][256 * 32];  // query tile, 2 x 16 KB
    __shared__ __align__(16) unsigned short BsBuf[2][64 * 32];   // support tile, 2 x 4 KB

    const int srow = lane >> 2;                       // row within 16-row group
    const int kb   = (lane & 3) ^ ((lane >> 3) & 3);  // swizzled k-block (0..3)

    // A: wave wid stages LDS rows [wid*64, wid*64+64) = its own m-rows; all
    // belong to ONE query (wid<2 -> q0, else q1).
    const unsigned short* awbase = (wid < 2) ? qb0 : qb1;
    int aoff[4];
#pragma unroll
    for (int g = 0; g < 4; ++g) {
        int row = (wid & 1) * 64 + g * 16 + srow;     // 0..127 within query
        int ml = row < HW ? row : HW - 1;
        aoff[g] = ml * CC + kb * 8;
    }
    // B: wave stages rows wid*16 .. wid*16+15 of the 64-row j-window
    const int jrow = wid * 16 + srow;
    const int ldsoA = wid * 4096 + lane * 16;         // + g*1024
    const int ldsoB = wid * 1024 + lane * 16;

    // stage one (ms0, c0) chunk (k=32): 5 async16 per wave (4 A + 1 B)
#define STAGE(ms0_, c0_, nb_)                                                        \
    {                                                                                \
        _Pragma("unroll")                                                            \
        for (int g = 0; g < 4; ++g)                                                  \
            async16(awbase + aoff[g] + (c0_), (char*)&AsBuf[nb_][0] + ldsoA + g * 1024);\
        int j_ = (ms0_) + jrow;                                                      \
        int jc_ = j_ < MS ? j_ : MS - 1;                                             \
        async16(sbase + jc_ * CC + kb * 8 + (c0_), (char*)&BsBuf[nb_][0] + ldsoB);   \
    }

    // per-lane top-3 state: 4 m-slots (transposed epilogue)
    float rt0[4], rt1[4], rt2[4]; int ra[4];
#pragma unroll
    for (int i = 0; i < 4; ++i) { rt0[i] = -INFINITY; rt1[i] = -INFINITY; rt2[i] = -INFINITY; ra[i] = 0; }

    f32x4 acc[4][4];   // [ji][qi]
#pragma unroll
    for (int ji = 0; ji < 4; ++ji)
#pragma unroll
        for (int qi = 0; qi < 4; ++qi)
#pragma unroll
            for (int r = 0; r < 4; ++r) acc[ji][qi][r] = 0.f;

    STAGE(0, 0, 0);
    int nb = 0;

    const int slot = l4 ^ ((l15 >> 1) & 3);           // read slot (0..3)
    const int aro  = (wm0 + l15) * 32 + slot * 8;     // ushort idx, + qi*512
    const int bro  = l15 * 32 + slot * 8;             // ushort idx, + ji*512

    // flat pipelined loop: chunk t -> ms0=(t/20)*64, c0=(t%20)*32 (200 chunks)
    for (int t = 0; t < 200; ++t) {
        const int tn = t + 1;
        if (tn < 200) {
            const int nms = (tn / 20) * 64;
            const int nc  = (tn % 20) * 32;
            STAGE(nms, nc, nb ^ 1);
            // wait only for chunk-t's 5 loads (issued one full chunk ago)
            asm volatile("s_waitcnt vmcnt(5)" ::: "memory");
        } else {
            asm volatile("s_waitcnt vmcnt(0)" ::: "memory");
        }
        __builtin_amdgcn_s_barrier();   // buffer nb fully resident for all waves

        // ---- compute: af[4] resident; bf read one-ahead ----
        short8 af[4];
#pragma unroll
        for (int qi = 0; qi < 4; ++qi)
            af[qi] = *(const short8*)(&AsBuf[nb][0] + aro + qi * 512);

        short8 bfA = *(const short8*)(&BsBuf[nb][0] + bro);
        __builtin_amdgcn_s_setprio(1);
#pragma unroll
        for (int ji = 0; ji < 4; ++ji) {
            short8 bfB;
            if (ji < 3) bfB = *(const short8*)(&BsBuf[nb][0] + bro + (ji + 1) * 512);
#pragma unroll
            for (int qi = 0; qi < 4; ++qi)
                acc[ji][qi] = __builtin_amdgcn_mfma_f32_16x16x32_bf16(
                    bfA, af[qi], acc[ji][qi], 0, 0, 0);   // D[j, m]
            bfA = bfB;
        }
        __builtin_amdgcn_s_setprio(0);
        nb ^= 1;

        if ((t % 20) == 19) {
            const int ms0 = (t / 20) * 64;
            // lane-local top-3; (ji,r) ascending == j ascending; strict >
            // keeps the first (smallest-j) max.
#pragma unroll
            for (int qi = 0; qi < 4; ++qi)
#pragma unroll
                for (int ji = 0; ji < 4; ++ji)
#pragma unroll
                    for (int r = 0; r < 4; ++r) {
                        const int jl = ms0 + ji * 16 + l4 * 4 + r;
                        float v = (jl < MS) ? acc[ji][qi][r] : -INFINITY;
                        const bool gt = v > rt0[qi];
                        ra[qi] = gt ? (n * MS + jl) : ra[qi];
                        const float m1 = fminf(rt0[qi], v);
                        rt0[qi] = fmaxf(rt0[qi], v);
                        const float m2 = fminf(rt1[qi], m1);
                        rt1[qi] = fmaxf(rt1[qi], m1);
                        rt2[qi] = fmaxf(rt2[qi], m2);
                    }
#pragma unroll
            for (int ji = 0; ji < 4; ++ji)
#pragma unroll
                for (int qi = 0; qi < 4; ++qi)
#pragma unroll
                    for (int r = 0; r < 4; ++r) acc[ji][qi][r] = 0.f;
        }

        __builtin_amdgcn_s_barrier();   // all reads of buf nb^1 done before
                                        // anyone overwrites it next iteration
    }

    // cross-l4 butterfly (masks 16,32): merge the 4 j-interleaved partitions.
    // Each wave owns its full j-range -> no cross-wave merge needed.
#pragma unroll
    for (int qi = 0; qi < 4; ++qi) {
#pragma unroll
        for (int mask = 16; mask <= 32; mask <<= 1) {
            const float o0 = __shfl_xor(rt0[qi], mask);
            const float o1 = __shfl_xor(rt1[qi], mask);
            const float o2 = __shfl_xor(rt2[qi], mask);
            const int   oa = __shfl_xor(ra[qi],  mask);
            const bool take = (o0 > rt0[qi]) || (o0 == rt0[qi] && oa < ra[qi]);
            ra[qi] = take ? oa : ra[qi];
            float m1 = fminf(rt0[qi], o0); rt0[qi] = fmaxf(rt0[qi], o0);
            float m2 = fminf(rt1[qi], m1); rt1[qi] = fmaxf(rt1[qi], m1);
            rt2[qi] = fmaxf(rt2[qi], m2);
            m1 = fminf(rt0[qi], o1); rt0[qi] = fmaxf(rt0[qi], o1);
            m2 = fminf(rt1[qi], m1); rt1[qi] = fmaxf(rt1[qi], m1);
            rt2[qi] = fmaxf(rt2[qi], m2);
            m1 = fminf(rt0[qi], o2); rt0[qi] = fmaxf(rt0[qi], o2);
            m2 = fminf(rt1[qi], m1); rt1[qi] = fmaxf(rt1[qi], m1);
            rt2[qi] = fmaxf(rt2[qi], m2);
        }
    }

    if (l4 == 0) {
#pragma unroll
        for (int qi = 0; qi < 4; ++qi) {
            const int m = wm0 + qi * 16 + l15;      // 0..255
            const int bqs = m >> 7;                 // which query of the pair
            const int ml  = m & 127;
            if (ml < HW && (bqs == 0 || !dup)) {
                const int bqx = bqs ? bq1 : bq0;
                float4 v; v.x = rt0[qi]; v.y = rt1[qi]; v.z = rt2[qi];
                v.w = __int_as_float(ra[qi]);
                pout[(bqx * NW + n) * HW + ml] = v;
            }
        }
    }
#undef STAGE
}

// ---------------------------------------------------------------------------
// Merge 5 per-n partials, mutual-NN mask, logits, per-query CE, atomic mean.
__global__ void merge_kernel(const float4* __restrict__ pout, const int* __restrict__ qy,
                             float* __restrict__ out)
{
    const int bq  = blockIdx.x;
    const int tid = threadIdx.x;   // 128 threads

    __shared__ float cw[128];
    __shared__ int   ag[128];
    __shared__ float tv[NW][128];
    __shared__ float maskf[128];
    __shared__ float lg[8];

    if (tid < HW) {
        float g0 = -INFINITY; int garg = 0;
#pragma unroll
        for (int n = 0; n < NW; ++n) {
            const float4 a = pout[(bq * NW + n) * HW + tid];
            if (a.x > g0) { g0 = a.x; garg = __float_as_int(a.w); }   // asc n = asc j
            tv[n][tid] = (a.x + a.y + a.z) * (1.f / 3.f);
        }
        cw[tid] = g0 + 1.0f;   // class_wise_max
        ag[tid] = garg;        // query_nearest (global j)
    }
    __syncthreads();
    if (tid < HW) {
        const float mycw = cw[tid];
        const int   myag = ag[tid];
        float ok = 1.f;
        for (int m2 = 0; m2 < HW; ++m2) {
            if (m2 == tid) continue;
            if (ag[m2] == myag) {
                float c2 = cw[m2];
                if (c2 > mycw || (c2 == mycw && m2 < tid)) ok = 0.f;  // first-max over mq
            }
        }
        maskf[tid] = ok;
    }
    __syncthreads();
    if (tid < NW) {
        float s = 0.f;
        for (int mq = 0; mq < HW; ++mq) s += maskf[mq] * tv[tid][mq];
        lg[tid] = s * 0.5f;   // / TEMPERATURE
    }
    __syncthreads();
    if (tid == 0) {
        float m = lg[0];
#pragma unroll
        for (int n2 = 1; n2 < NW; ++n2) m = fmaxf(m, lg[n2]);
        float se = 0.f;
#pragma unroll
        for (int n2 = 0; n2 < NW; ++n2) se += expf(lg[n2] - m);
        int y = qy[bq];
        atomicAdd(out, -(lg[y] - m - logf(se)) * (1.f / NBQ));
    }
}

// ---------------------------------------------------------------------------
extern "C" void kernel_launch(void* const* d_in, const int* in_sizes, int n_in,
                              void* d_out, int out_size, void* d_ws, size_t ws_size,
                              hipStream_t stream)
{
    const float* sup = (const float*)d_in[0];   // [4][25][640][121]
    const float* qry = (const float*)d_in[1];   // [4][75][640][121]
    const int*   qy  = (const int*)d_in[3];     // [4][75]
    float* out = (float*)d_out;
    float* ws  = (float*)d_ws;

    __hip_bfloat16* Sbf = (__hip_bfloat16*)(ws + OFF_SBF);
    __hip_bfloat16* Qbf = (__hip_bfloat16*)(ws + OFF_QBF);
    float4* pout = (float4*)(ws + OFF_P);
    float*  nrm  = (float*)(ws + OFF_NRM);   // aliases pout region (dead by then)

    hipLaunchKernelGGL(norm_kernel,  dim3((BB * SS + NBQ) * 4), dim3(128), 0, stream,
                       sup, qry, nrm, out);
    hipLaunchKernelGGL(scale_kernel, dim3((BB * SS + NBQ) * 4), dim3(256), 0, stream,
                       sup, qry, nrm, Sbf, Qbf);
    hipLaunchKernelGGL(simi_kernel, dim3(8 * PAIRS_PER_XCD * NW), dim3(256), 0, stream,
                       Sbf, Qbf, pout);
    hipLaunchKernelGGL(merge_kernel, dim3(NBQ), dim3(128), 0, stream, pout, qy, out);
}